// Round 1
// baseline (436.352 us; speedup 1.0000x reference)
//
#include <hip/hip_runtime.h>

// Equivariant 3D conv, fused:
//   out = sc + conv(x, K)  ==  conv(x, K') where K' has sc folded into center tap.
// x: (8,32,32,32,32) f32 NXYZC ; out: (8,32,32,32,64) f32
// K[t][i][o], t = a*9+b*3+c (lattice offsets a,b,c in {0,1,2} -> dx-1 etc.)
// Corner taps (dist=sqrt(3)) are exactly zero in the reference -> skipped.

__device__ __forceinline__ float sus_f(float v) {
    return v > 0.f ? __expf(-1.f / v) : 0.f;
}

__global__ __launch_bounds__(256) void conv_e3nn_kernel(
    const float* __restrict__ x,
    const float* __restrict__ w_lin0,
    const float* __restrict__ w_lin1,
    const float* __restrict__ w000,
    const float* __restrict__ w011,
    const float* __restrict__ w101,
    const float* __restrict__ w110,
    float* __restrict__ out)
{
    __shared__ float kl[2048];            // K[t] slice: [i=32][o=64]
    const int tid = threadIdx.x;
    const int bid = blockIdx.x;
    // block -> (n, X, Yt):  grid = 8*32*4
    const int Yt = bid & 3;
    const int X  = (bid >> 2) & 31;
    const int n  = bid >> 7;
    const int yl = tid >> 5;              // 0..7
    const int z  = tid & 31;
    const int y  = Yt * 8 + yl;

    float4 acc[16];
    #pragma unroll
    for (int i = 0; i < 16; ++i) acc[i] = make_float4(0.f, 0.f, 0.f, 0.f);

    // staging decode: this thread fills kl[tid*8 .. tid*8+7]  (i = tid/8, o = (tid%8)*8 + j)
    const int si  = tid >> 3;
    const int so8 = (tid & 7) * 8;

    #pragma unroll 1
    for (int t = 0; t < 27; ++t) {
        const int a = t / 9, b = (t / 3) % 3, c = t % 3;
        // corner taps: radial basis is exactly zero -> skip (uniform branch, no sync inside)
        if (a != 1 && b != 1 && c != 1) continue;

        __syncthreads();   // protect kl from previous tap's readers
        // ---- compute K[t] slice into LDS ----
        {
            const float fx = (float)(a - 1), fy = (float)(b - 1), fz = (float)(c - 1);
            const float dist = sqrtf(fx * fx + fy * fy + fz * fz);
            float emb[4];
            #pragma unroll
            for (int r = 0; r < 4; ++r) {
                const float v = 0.3f * (float)(r + 1);
                const float d = (dist - v) * (1.0f / 0.3f);
                emb[r] = 8.4335731f * sus_f(d + 1.f) * sus_f(1.f - d);
            }
            const float s = (dist > 0.f) ? (1.7320508f / dist) : 0.f;
            const float shv[3] = { fx * s, fy * s, fz * s };
            const float S000 = 0.25f / 27.f;                   // alpha / n_lat
            const float S1   = 0.25f * 0.57735027f / 27.f;     // alpha * inv_s3 / n_lat
            const float LNRM = 0.35355339f;                    // 1/sqrt(8)

            const int i = si;
            #pragma unroll
            for (int j = 0; j < 8; ++j) {
                const int o = so8 + j;
                float val;
                if (i < 8) {
                    const int u = i;
                    if (o < 16) {
                        const int w = o;
                        const float* p = w000 + u * 16 + w;
                        val = S000 * (emb[0]*p[0] + emb[1]*p[128] + emb[2]*p[256] + emb[3]*p[384]);
                        if (t == 13) val += LNRM * w_lin0[u * 16 + w];
                    } else {
                        const int oo = o - 16, w = oo / 3, m = oo % 3;
                        const float* p = w011 + u * 16 + w;
                        val = S1 * shv[m] * (emb[0]*p[0] + emb[1]*p[128] + emb[2]*p[256] + emb[3]*p[384]);
                    }
                } else {
                    const int iu = i - 8, u = iu / 3, ic = iu % 3;
                    if (o < 16) {
                        const int w = o;
                        const float* p = w110 + u * 16 + w;
                        val = S1 * shv[ic] * (emb[0]*p[0] + emb[1]*p[128] + emb[2]*p[256] + emb[3]*p[384]);
                    } else {
                        const int oo = o - 16, w = oo / 3, m = oo % 3;
                        if (ic == m) {
                            const float* p = w101 + u * 16 + w;
                            val = S1 * (emb[0]*p[0] + emb[1]*p[128] + emb[2]*p[256] + emb[3]*p[384]);
                            if (t == 13) val += LNRM * w_lin1[u * 16 + w];
                        } else {
                            val = 0.f;
                        }
                    }
                }
                kl[tid * 8 + j] = val;
            }
        }
        __syncthreads();

        // ---- accumulate this tap ----
        const int xx = X + a - 1, yy = y + b - 1, zz = z + c - 1;
        if ((unsigned)xx < 32u && (unsigned)yy < 32u && (unsigned)zz < 32u) {
            const float4* xp = reinterpret_cast<const float4*>(
                x + ((((n * 32 + xx) * 32 + yy) * 32 + zz) << 5));
            const float4* kl4 = reinterpret_cast<const float4*>(kl);
            // prefetch the voxel's 32 input channels (static-indexed -> stays in regs)
            float4 xr[8];
            #pragma unroll
            for (int c4 = 0; c4 < 8; ++c4) xr[c4] = xp[c4];
            #pragma unroll
            for (int c4 = 0; c4 < 8; ++c4) {
                const float4 xq = xr[c4];
                #pragma unroll
                for (int s4 = 0; s4 < 4; ++s4) {
                    const float xv = (s4 == 0) ? xq.x : (s4 == 1) ? xq.y : (s4 == 2) ? xq.z : xq.w;
                    const int ci = c4 * 4 + s4;
                    #pragma unroll
                    for (int o4 = 0; o4 < 16; ++o4) {
                        const float4 k4 = kl4[ci * 16 + o4];   // wave-uniform -> LDS broadcast
                        acc[o4].x += xv * k4.x;
                        acc[o4].y += xv * k4.y;
                        acc[o4].z += xv * k4.z;
                        acc[o4].w += xv * k4.w;
                    }
                }
            }
        }
    }

    float4* op = reinterpret_cast<float4*>(out + (((n * 32 + X) * 32 + y) * 32 + z) * 64);
    #pragma unroll
    for (int o4 = 0; o4 < 16; ++o4) op[o4] = acc[o4];
}

extern "C" void kernel_launch(void* const* d_in, const int* in_sizes, int n_in,
                              void* d_out, int out_size, void* d_ws, size_t ws_size,
                              hipStream_t stream) {
    const float* x    = (const float*)d_in[0];
    const float* wl0  = (const float*)d_in[1];
    const float* wl1  = (const float*)d_in[2];
    const float* w000 = (const float*)d_in[3];
    const float* w011 = (const float*)d_in[4];
    const float* w101 = (const float*)d_in[5];
    const float* w110 = (const float*)d_in[6];
    float* out = (float*)d_out;

    conv_e3nn_kernel<<<dim3(8 * 32 * 4), dim3(256), 0, stream>>>(
        x, wl0, wl1, w000, w011, w101, w110, out);
}

// Round 2
// 51.406 us; speedup vs baseline: 8.4883x; 8.4883x over previous
//
#include <hip/hip_runtime.h>

// Implicit-GEMM MFMA version.
// out = conv(x, K') where K' (19 non-corner taps) has the sc linear folded
// into the center tap. K' precomputed to d_ws in bf16 B-fragment layout.
// Main kernel: block = (n, X, Yg). x-tile staged once to LDS (bf16, zero
// halos), then a barrier-free 19-tap MFMA loop; 4 waves x (1y,32z) x 64 outs.

typedef __attribute__((ext_vector_type(8))) short bf16x8;
typedef __attribute__((ext_vector_type(4))) float f32x4;

__device__ __forceinline__ float sus_f(float v) { return v > 0.f ? __expf(-1.f / v) : 0.f; }

__device__ __forceinline__ unsigned short f2bf(float f) {
    union { float f; unsigned u; } c; c.f = f;
    unsigned u = c.u;
    u += 0x7FFFu + ((u >> 16) & 1u);          // round-to-nearest-even
    return (unsigned short)(u >> 16);
}

// ---------------- k precompute: 19 blocks x 256 threads ----------------
// d_ws layout (bf16): frag[ta][nt][lane=64][slot=8]
//   value = K[t][ci = 8*(lane>>4) + slot][o = 16*nt + (lane&15)]
__global__ __launch_bounds__(256) void prep_k(
    const float* __restrict__ w_lin0, const float* __restrict__ w_lin1,
    const float* __restrict__ w000,  const float* __restrict__ w011,
    const float* __restrict__ w101,  const float* __restrict__ w110,
    unsigned short* __restrict__ kw)
{
    const int taps[19] = {1,3,4,5,7,9,10,11,12,13,14,15,16,17,19,21,22,23,25};
    const int ta = blockIdx.x;
    const int t = taps[ta];
    const int a = t / 9, b = (t / 3) % 3, c = t % 3;

    const float fx = (float)(a - 1), fy = (float)(b - 1), fz = (float)(c - 1);
    const float dist = sqrtf(fx * fx + fy * fy + fz * fz);
    float emb[4];
    #pragma unroll
    for (int r = 0; r < 4; ++r) {
        const float v = 0.3f * (float)(r + 1);
        const float d = (dist - v) * (1.0f / 0.3f);
        emb[r] = 8.4335731f * sus_f(d + 1.f) * sus_f(1.f - d);
    }
    const float s = (dist > 0.f) ? (1.7320508f / dist) : 0.f;
    const float shv[3] = { fx * s, fy * s, fz * s };
    const float S000 = 0.25f / 27.f;
    const float S1   = 0.25f * 0.57735027f / 27.f;
    const float LNRM = 0.35355339f;

    const int tid = threadIdx.x;
    const int ci = tid >> 3;

    #pragma unroll
    for (int j = 0; j < 8; ++j) {
        const int o = (tid & 7) * 8 + j;
        float val;
        if (ci < 8) {
            const int u = ci;
            if (o < 16) {
                const float* p = w000 + u * 16 + o;
                val = S000 * (emb[0]*p[0] + emb[1]*p[128] + emb[2]*p[256] + emb[3]*p[384]);
                if (t == 13) val += LNRM * w_lin0[u * 16 + o];
            } else {
                const int oo = o - 16, w = oo / 3, m = oo % 3;
                const float* p = w011 + u * 16 + w;
                val = S1 * shv[m] * (emb[0]*p[0] + emb[1]*p[128] + emb[2]*p[256] + emb[3]*p[384]);
            }
        } else {
            const int iu = ci - 8, u = iu / 3, ic = iu % 3;
            if (o < 16) {
                const float* p = w110 + u * 16 + o;
                val = S1 * shv[ic] * (emb[0]*p[0] + emb[1]*p[128] + emb[2]*p[256] + emb[3]*p[384]);
            } else {
                const int oo = o - 16, w = oo / 3, m = oo % 3;
                if (ic == m) {
                    const float* p = w101 + u * 16 + w;
                    val = S1 * (emb[0]*p[0] + emb[1]*p[128] + emb[2]*p[256] + emb[3]*p[384]);
                    if (t == 13) val += LNRM * w_lin1[u * 16 + w];
                } else {
                    val = 0.f;
                }
            }
        }
        const int g = ci >> 3, slot = ci & 7, nt = o >> 4, cc = o & 15;
        const int l = (g << 4) | cc;
        kw[((size_t)(ta * 4 + nt) * 64 + l) * 8 + slot] = f2bf(val);
    }
}

// ---------------- main conv kernel ----------------
// LDS x-tile: [dx=3][y6=6][zp=34][ci=32] bf16  (zp has zero pads at 0 and 33)
#define LXI(dx, y6, zp, ci) ((((dx) * 6 + (y6)) * 34 + (zp)) * 32 + (ci))

__global__ __launch_bounds__(256) void conv_mfma(
    const float* __restrict__ x,
    const unsigned short* __restrict__ kw,
    float* __restrict__ out)
{
    __shared__ unsigned short lx[3 * 6 * 34 * 32];   // 39168 B

    // XCD-friendly decode: bid%8 constant per (n,X) group of 8 Yg-blocks;
    // each XCD handles one batch n with X sweeping 0..31 (L2 plane reuse).
    const int bid = blockIdx.x;
    const int x8 = bid & 7;
    const int j  = bid >> 3;
    const int p  = x8 * 32 + (j >> 3);
    const int Yg = j & 7;
    const int n  = p >> 5;
    const int X  = p & 31;
    const int y0 = Yg * 4;
    const int tid = threadIdx.x;

    // ---- stage x-tile (f32 -> bf16), zero halos ----
    for (int r = tid; r < 576; r += 256) {
        const int dx = r / 192, rem = r - dx * 192;
        const int y6 = rem >> 5, z = rem & 31;
        const int gx = X + dx - 1, gy = y0 + y6 - 1;
        bf16x8 v[4];
        if ((unsigned)gx < 32u && (unsigned)gy < 32u) {
            const float4* sp = reinterpret_cast<const float4*>(
                x + ((size_t)(((n * 32 + gx) * 32 + gy) * 32 + z) << 5));
            #pragma unroll
            for (int q = 0; q < 4; ++q) {
                const float4 lo = sp[2 * q], hi = sp[2 * q + 1];
                bf16x8 w;
                w[0] = (short)f2bf(lo.x); w[1] = (short)f2bf(lo.y);
                w[2] = (short)f2bf(lo.z); w[3] = (short)f2bf(lo.w);
                w[4] = (short)f2bf(hi.x); w[5] = (short)f2bf(hi.y);
                w[6] = (short)f2bf(hi.z); w[7] = (short)f2bf(hi.w);
                v[q] = w;
            }
        } else {
            #pragma unroll
            for (int q = 0; q < 4; ++q) v[q] = (bf16x8)(short)0;
        }
        bf16x8* dp = reinterpret_cast<bf16x8*>(&lx[LXI(dx, y6, z + 1, 0)]);
        #pragma unroll
        for (int q = 0; q < 4; ++q) dp[q] = v[q];
    }
    // zero the zp=0 and zp=33 pad rows (36 rows x 32 elems)
    if (tid < 36) {
        const int dxy = tid >> 1, zp = (tid & 1) * 33;
        bf16x8* dp = reinterpret_cast<bf16x8*>(&lx[(dxy * 34 + zp) * 32]);
        #pragma unroll
        for (int q = 0; q < 4; ++q) dp[q] = (bf16x8)(short)0;
    }
    __syncthreads();

    // ---- barrier-free tap loop ----
    const int wid = tid >> 6;        // wave owns y = y0 + wid
    const int l   = tid & 63;
    const int lr  = l & 15;          // A row / C col
    const int lg  = l >> 4;          // k-group

    f32x4 acc[2][4];
    #pragma unroll
    for (int r = 0; r < 2; ++r)
        #pragma unroll
        for (int nt = 0; nt < 4; ++nt) acc[r][nt] = (f32x4)0.f;

    const bf16x8* kwf = reinterpret_cast<const bf16x8*>(kw);
    const int taps[19] = {1,3,4,5,7,9,10,11,12,13,14,15,16,17,19,21,22,23,25};

    #pragma unroll
    for (int ta = 0; ta < 19; ++ta) {
        const int t = taps[ta];
        const int a = t / 9, b = (t / 3) % 3, c = t % 3;   // 0..2 (slot = offset+1)

        bf16x8 bf[4];
        #pragma unroll
        for (int nt = 0; nt < 4; ++nt) bf[nt] = kwf[(size_t)(ta * 4 + nt) * 64 + l];

        #pragma unroll
        for (int r = 0; r < 2; ++r) {
            const bf16x8 af = *reinterpret_cast<const bf16x8*>(
                &lx[LXI(a, wid + b, 16 * r + lr + c, 8 * lg)]);
            #pragma unroll
            for (int nt = 0; nt < 4; ++nt)
                acc[r][nt] = __builtin_amdgcn_mfma_f32_16x16x32_bf16(af, bf[nt], acc[r][nt], 0, 0, 0);
        }
    }

    // ---- epilogue: C layout col = lane&15, row = (lane>>4)*4 + reg ----
    float* ob = out + ((size_t)(((n * 32 + X) * 32 + (y0 + wid)) * 32) << 6);
    #pragma unroll
    for (int r = 0; r < 2; ++r)
        #pragma unroll
        for (int nt = 0; nt < 4; ++nt)
            #pragma unroll
            for (int reg = 0; reg < 4; ++reg) {
                const int z = 16 * r + 4 * lg + reg;
                ob[((size_t)z << 6) + 16 * nt + lr] = acc[r][nt][reg];
            }
}

extern "C" void kernel_launch(void* const* d_in, const int* in_sizes, int n_in,
                              void* d_out, int out_size, void* d_ws, size_t ws_size,
                              hipStream_t stream) {
    const float* x    = (const float*)d_in[0];
    const float* wl0  = (const float*)d_in[1];
    const float* wl1  = (const float*)d_in[2];
    const float* w000 = (const float*)d_in[3];
    const float* w011 = (const float*)d_in[4];
    const float* w101 = (const float*)d_in[5];
    const float* w110 = (const float*)d_in[6];
    float* out = (float*)d_out;
    unsigned short* kw = (unsigned short*)d_ws;   // needs 19*4*64*8*2 = 77824 B

    prep_k<<<dim3(19), dim3(256), 0, stream>>>(wl0, wl1, w000, w011, w101, w110, kw);
    conv_mfma<<<dim3(8 * 32 * 8), dim3(256), 0, stream>>>(x, kw, out);
}

// Round 3
// 45.344 us; speedup vs baseline: 9.6231x; 1.1337x over previous
//
#include <hip/hip_runtime.h>

// Implicit-GEMM MFMA conv, round 3.
//  - prep_k: K' (19 non-corner taps, sc folded into center) -> bf16 B-frags in d_ws
//  - xcvt:   x f32 -> bf16 in d_ws, PRE-SWIZZLED (slot ^= ((z+1)>>1)&3 per 16B group)
//  - conv_mfma<true>: Yg=8 tile (LDS 65280B, 2 blk/CU), async global_load_lds staging,
//    M=64/wave, B-frag register double-buffer, swizzled (bank-conflict-free) A-reads.
//  - conv_mfma<false>: fallback if ws too small: reg-staged f32->bf16, same LDS layout.

typedef __attribute__((ext_vector_type(8))) short bf16x8;
typedef __attribute__((ext_vector_type(4))) float f32x4;
typedef unsigned int u32;

__device__ __forceinline__ float sus_f(float v) { return v > 0.f ? __expf(-1.f / v) : 0.f; }

__device__ __forceinline__ unsigned short f2bf(float f) {
    union { float f; unsigned u; } c; c.f = f;
    unsigned u = c.u;
    u += 0x7FFFu + ((u >> 16) & 1u);          // round-to-nearest-even
    return (unsigned short)(u >> 16);
}

// ---------------- k precompute: 19 blocks x 256 threads ----------------
// kw layout (bf16): frag[ta][nt][lane=64][slot=8]
//   value = K[t][ci = 8*(lane>>4) + slot][o = 16*nt + (lane&15)]
__global__ __launch_bounds__(256) void prep_k(
    const float* __restrict__ w_lin0, const float* __restrict__ w_lin1,
    const float* __restrict__ w000,  const float* __restrict__ w011,
    const float* __restrict__ w101,  const float* __restrict__ w110,
    unsigned short* __restrict__ kw)
{
    const int taps[19] = {1,3,4,5,7,9,10,11,12,13,14,15,16,17,19,21,22,23,25};
    const int ta = blockIdx.x;
    const int t = taps[ta];
    const int a = t / 9, b = (t / 3) % 3, c = t % 3;

    const float fx = (float)(a - 1), fy = (float)(b - 1), fz = (float)(c - 1);
    const float dist = sqrtf(fx * fx + fy * fy + fz * fz);
    float emb[4];
    #pragma unroll
    for (int r = 0; r < 4; ++r) {
        const float v = 0.3f * (float)(r + 1);
        const float d = (dist - v) * (1.0f / 0.3f);
        emb[r] = 8.4335731f * sus_f(d + 1.f) * sus_f(1.f - d);
    }
    const float s = (dist > 0.f) ? (1.7320508f / dist) : 0.f;
    const float shv[3] = { fx * s, fy * s, fz * s };
    const float S000 = 0.25f / 27.f;
    const float S1   = 0.25f * 0.57735027f / 27.f;
    const float LNRM = 0.35355339f;

    const int tid = threadIdx.x;
    const int ci = tid >> 3;

    #pragma unroll
    for (int j = 0; j < 8; ++j) {
        const int o = (tid & 7) * 8 + j;
        float val;
        if (ci < 8) {
            const int u = ci;
            if (o < 16) {
                const float* p = w000 + u * 16 + o;
                val = S000 * (emb[0]*p[0] + emb[1]*p[128] + emb[2]*p[256] + emb[3]*p[384]);
                if (t == 13) val += LNRM * w_lin0[u * 16 + o];
            } else {
                const int oo = o - 16, w = oo / 3, m = oo % 3;
                const float* p = w011 + u * 16 + w;
                val = S1 * shv[m] * (emb[0]*p[0] + emb[1]*p[128] + emb[2]*p[256] + emb[3]*p[384]);
            }
        } else {
            const int iu = ci - 8, u = iu / 3, ic = iu % 3;
            if (o < 16) {
                const float* p = w110 + u * 16 + o;
                val = S1 * shv[ic] * (emb[0]*p[0] + emb[1]*p[128] + emb[2]*p[256] + emb[3]*p[384]);
            } else {
                const int oo = o - 16, w = oo / 3, m = oo % 3;
                if (ic == m) {
                    const float* p = w101 + u * 16 + w;
                    val = S1 * (emb[0]*p[0] + emb[1]*p[128] + emb[2]*p[256] + emb[3]*p[384]);
                    if (t == 13) val += LNRM * w_lin1[u * 16 + w];
                } else {
                    val = 0.f;
                }
            }
        }
        const int g = ci >> 3, slot = ci & 7, nt = o >> 4, cc = o & 15;
        const int lane = (g << 4) | cc;
        kw[((size_t)(ta * 4 + nt) * 64 + lane) * 8 + slot] = f2bf(val);
    }
}

// ---------------- x f32 -> bf16, pre-swizzled ----------------
// xb layout: per (n,gx,gy) row: 32 z * 4 slots * 8 elems; slot s holds ci-group
// s ^ (((z+1)>>1)&3)  (matches linear global_load_lds + swizzled ds_read).
__global__ __launch_bounds__(256) void xcvt(
    const float* __restrict__ x, unsigned short* __restrict__ xb)
{
    const int gi = blockIdx.x * 256 + threadIdx.x;   // 16B-group id, 0..2^20-1
    const int vox = gi >> 2, g = gi & 3;
    const int gz = vox & 31;
    const float4* sp = reinterpret_cast<const float4*>(x) + (size_t)gi * 2;
    const float4 lo = sp[0], hi = sp[1];
    bf16x8 w;
    w[0] = (short)f2bf(lo.x); w[1] = (short)f2bf(lo.y);
    w[2] = (short)f2bf(lo.z); w[3] = (short)f2bf(lo.w);
    w[4] = (short)f2bf(hi.x); w[5] = (short)f2bf(hi.y);
    w[6] = (short)f2bf(hi.z); w[7] = (short)f2bf(hi.w);
    const int slot = g ^ (((gz + 1) >> 1) & 3);
    const size_t dst = ((size_t)(vox >> 5) << 10) + (gz << 5) + (slot << 3);
    *reinterpret_cast<bf16x8*>(xb + dst) = w;
}

// ---------------- main conv kernel ----------------
// LDS tile: [dx=3][y10=10][zp=34][ci=32] bf16 (zp 0/33 are zero pads), 65280 B.
// Within a (dx,y10,zp) row, 16B ci-groups are stored at slot ^ ((zp>>1)&3).
template<bool DIRECT>
__global__ __launch_bounds__(256, 2) void conv_mfma(
    const float* __restrict__ x,
    const unsigned short* __restrict__ xb,
    const unsigned short* __restrict__ kw,
    float* __restrict__ out)
{
    __shared__ unsigned short lx[3 * 10 * 34 * 32];   // 65280 B

    const int tid = threadIdx.x;
    const int bid = blockIdx.x;
    // XCD swizzle: 1024 blocks, bid&7 = XCD -> each XCD owns one batch n,
    // X sweeping sequentially (3-plane working set stays in its L2).
    const int xcd = bid & 7, idx = bid >> 3;
    const int gid = xcd * 128 + idx;
    const int n = gid >> 7, X = (gid >> 2) & 31, Yg = gid & 3;
    const int Y0 = Yg * 8;
    const int wid = tid >> 6, l = tid & 63, lr = l & 15, lg = l >> 4;

    // zero-fill tile (covers halos + pads)
    f32x4* lz = reinterpret_cast<f32x4*>(lx);
    #pragma unroll
    for (int i = 0; i < 16; ++i) {
        const int j = tid + i * 256;
        if (j < 4080) lz[j] = (f32x4)0.f;
    }
    __syncthreads();

    if (DIRECT) {
        // async staging: 30 rows, each = 2048B contiguous in xb and in LDS
        #pragma unroll
        for (int k = 0; k < 8; ++k) {
            const int rr = wid + (k << 2);
            if (rr < 30) {
                const int dx = rr / 10, y6 = rr - dx * 10;
                const int gx = X + dx - 1, gy = Y0 + y6 - 1;
                if ((unsigned)gx < 32u && (unsigned)gy < 32u) {
                    const char* src = reinterpret_cast<const char*>(xb) +
                        ((size_t)((n * 32 + gx) * 32 + gy) << 11);
                    char* dstrow = reinterpret_cast<char*>(lx) + rr * 2176 + 64;
                    __builtin_amdgcn_global_load_lds(
                        (const __attribute__((address_space(1))) u32*)(src + l * 16),
                        (__attribute__((address_space(3))) u32*)(dstrow), 16, 0, 0);
                    __builtin_amdgcn_global_load_lds(
                        (const __attribute__((address_space(1))) u32*)(src + 1024 + l * 16),
                        (__attribute__((address_space(3))) u32*)(dstrow + 1024), 16, 0, 0);
                }
            }
        }
    } else {
        // fallback: reg-staged f32 -> bf16, same swizzled layout
        for (int it = tid; it < 960; it += 256) {
            const int dx = it / 320, rem = it - dx * 320;
            const int y6 = rem >> 5, z = rem & 31;
            const int gx = X + dx - 1, gy = Y0 + y6 - 1;
            if ((unsigned)gx < 32u && (unsigned)gy < 32u) {
                const float4* sp = reinterpret_cast<const float4*>(
                    x + ((size_t)(((n * 32 + gx) * 32 + gy) * 32 + z) << 5));
                const int swz = ((z + 1) >> 1) & 3;
                char* row = reinterpret_cast<char*>(lx) + (dx * 10 + y6) * 2176 + (z + 1) * 64;
                #pragma unroll
                for (int g = 0; g < 4; ++g) {
                    const float4 lo = sp[2 * g], hi = sp[2 * g + 1];
                    bf16x8 w;
                    w[0] = (short)f2bf(lo.x); w[1] = (short)f2bf(lo.y);
                    w[2] = (short)f2bf(lo.z); w[3] = (short)f2bf(lo.w);
                    w[4] = (short)f2bf(hi.x); w[5] = (short)f2bf(hi.y);
                    w[6] = (short)f2bf(hi.z); w[7] = (short)f2bf(hi.w);
                    *reinterpret_cast<bf16x8*>(row + ((g ^ swz) << 4)) = w;
                }
            }
        }
    }
    __syncthreads();

    // ---- barrier-free tap loop; wave owns y-pair (Y0+2*wid, +1), M=64 ----
    constexpr int TA[19] = {1,3,4,5,7,9,10,11,12,13,14,15,16,17,19,21,22,23,25};
    const bf16x8* kwf = reinterpret_cast<const bf16x8*>(kw);
    const char* lxc = reinterpret_cast<const char*>(lx);
    const int yloc = wid * 2;

    f32x4 acc[4][4];
    #pragma unroll
    for (int r = 0; r < 4; ++r)
        #pragma unroll
        for (int nt = 0; nt < 4; ++nt) acc[r][nt] = (f32x4)0.f;

    bf16x8 bcur[4];
    #pragma unroll
    for (int nt = 0; nt < 4; ++nt) bcur[nt] = kwf[(size_t)nt * 64 + l];

    #pragma unroll
    for (int ta = 0; ta < 19; ++ta) {
        const int t = TA[ta];
        const int a = t / 9, b = (t / 3) % 3, c = t % 3;

        bf16x8 bnext[4];
        if (ta < 18) {
            #pragma unroll
            for (int nt = 0; nt < 4; ++nt)
                bnext[nt] = kwf[(size_t)((ta + 1) * 4 + nt) * 64 + l];
        }

        #pragma unroll
        for (int r = 0; r < 4; ++r) {
            const int y10 = yloc + (r >> 1) + b;
            const int zp = 16 * (r & 1) + lr + c;
            const int byte = ((a * 10 + y10) * 34 + zp) * 64 + ((lg ^ ((zp >> 1) & 3)) << 4);
            const bf16x8 af = *reinterpret_cast<const bf16x8*>(lxc + byte);
            #pragma unroll
            for (int nt = 0; nt < 4; ++nt)
                acc[r][nt] = __builtin_amdgcn_mfma_f32_16x16x32_bf16(af, bcur[nt], acc[r][nt], 0, 0, 0);
        }

        if (ta < 18) {
            #pragma unroll
            for (int nt = 0; nt < 4; ++nt) bcur[nt] = bnext[nt];
        }
    }

    // ---- epilogue: C col(lane&15)=out-channel block, row=(lane>>4)*4+reg=z ----
    float* ob = out + ((size_t)(((n * 32 + X) * 32 + Y0 + yloc) * 32) << 6);
    #pragma unroll
    for (int r = 0; r < 4; ++r) {
        float* oy = ob + (size_t)(r >> 1) * 2048;
        #pragma unroll
        for (int nt = 0; nt < 4; ++nt)
            #pragma unroll
            for (int reg = 0; reg < 4; ++reg) {
                const int z = 16 * (r & 1) + 4 * lg + reg;
                oy[z * 64 + nt * 16 + lr] = acc[r][nt][reg];
            }
    }
}

extern "C" void kernel_launch(void* const* d_in, const int* in_sizes, int n_in,
                              void* d_out, int out_size, void* d_ws, size_t ws_size,
                              hipStream_t stream) {
    const float* x    = (const float*)d_in[0];
    const float* wl0  = (const float*)d_in[1];
    const float* wl1  = (const float*)d_in[2];
    const float* w000 = (const float*)d_in[3];
    const float* w011 = (const float*)d_in[4];
    const float* w101 = (const float*)d_in[5];
    const float* w110 = (const float*)d_in[6];
    float* out = (float*)d_out;

    unsigned short* kw = (unsigned short*)d_ws;
    const size_t KWB = 77824;               // 19*4*64*8*2
    const size_t XBB = 16777216ull;         // 8*32^3*32*2

    prep_k<<<dim3(19), dim3(256), 0, stream>>>(wl0, wl1, w000, w011, w101, w110, kw);

    if (ws_size >= KWB + XBB) {
        unsigned short* xb = (unsigned short*)((char*)d_ws + KWB);
        xcvt<<<dim3(4096), dim3(256), 0, stream>>>(x, xb);
        conv_mfma<true><<<dim3(1024), dim3(256), 0, stream>>>(x, xb, kw, out);
    } else {
        conv_mfma<false><<<dim3(1024), dim3(256), 0, stream>>>(x, nullptr, kw, out);
    }
}

// Round 5
// 42.351 us; speedup vs baseline: 10.3031x; 1.0707x over previous
//
#include <hip/hip_runtime.h>

// Implicit-GEMM MFMA conv, round 5 (round 4 + B-ring fix: size-4 ring).
//  - prep_all: (a) x f32 -> bf16 pre-swizzled into d_ws (4096 blocks)
//              (b) K' 19-tap bf16 B-frags into d_ws (19 blocks), sc folded into center tap
//  - conv_mfma<true>: Yg=8 tile (LDS 65280B), async global_load_lds staging,
//    M=64/wave, depth-3 prefetch into a SIZE-4 B-frag register ring
//    (size-3 ring aliased current slot -> round-4 correctness bug),
//    batched A ds_reads, pad-only zeroing.
//  - conv_mfma<false>: fallback if ws too small (reg-staged f32->bf16, same layout).

typedef __attribute__((ext_vector_type(8))) short bf16x8;
typedef __attribute__((ext_vector_type(4))) float f32x4;
typedef unsigned int u32;

__device__ __forceinline__ float sus_f(float v) { return v > 0.f ? __expf(-1.f / v) : 0.f; }

__device__ __forceinline__ unsigned short f2bf(float f) {
    union { float f; unsigned u; } c; c.f = f;
    unsigned u = c.u;
    u += 0x7FFFu + ((u >> 16) & 1u);          // round-to-nearest-even
    return (unsigned short)(u >> 16);
}

// ---------------- fused precompute ----------------
// koff = number of xcvt blocks ahead of the 19 prep_k blocks (0 in fallback).
// xb layout: per (n,gx,gy) row: 32 z * 4 slots * 8 elems; group g stored at
//   slot = g ^ (((z+1)>>1)&3)
// kw layout (bf16): frag[ta][nt][lane=64][slot=8]
//   value = K[t][ci = 8*(lane>>4) + slot][o = 16*nt + (lane&15)]
__global__ __launch_bounds__(256) void prep_all(
    const float* __restrict__ x,
    const float* __restrict__ w_lin0, const float* __restrict__ w_lin1,
    const float* __restrict__ w000,  const float* __restrict__ w011,
    const float* __restrict__ w101,  const float* __restrict__ w110,
    unsigned short* __restrict__ xb, unsigned short* __restrict__ kw,
    int koff)
{
    const int bid = blockIdx.x;
    const int tid = threadIdx.x;

    if (bid < koff) {
        // ---- x conversion ----
        const int gi = bid * 256 + tid;          // 16B-group id
        const int vox = gi >> 2, g = gi & 3;
        const int gz = vox & 31;
        const float4* sp = reinterpret_cast<const float4*>(x) + (size_t)gi * 2;
        const float4 lo = sp[0], hi = sp[1];
        bf16x8 w;
        w[0] = (short)f2bf(lo.x); w[1] = (short)f2bf(lo.y);
        w[2] = (short)f2bf(lo.z); w[3] = (short)f2bf(lo.w);
        w[4] = (short)f2bf(hi.x); w[5] = (short)f2bf(hi.y);
        w[6] = (short)f2bf(hi.z); w[7] = (short)f2bf(hi.w);
        const int slot = g ^ (((gz + 1) >> 1) & 3);
        const size_t dst = ((size_t)(vox >> 5) << 10) + (gz << 5) + (slot << 3);
        *reinterpret_cast<bf16x8*>(xb + dst) = w;
        return;
    }

    // ---- K' fragments ----
    const int taps[19] = {1,3,4,5,7,9,10,11,12,13,14,15,16,17,19,21,22,23,25};
    const int ta = bid - koff;
    const int t = taps[ta];
    const int a = t / 9, b = (t / 3) % 3, c = t % 3;

    const float fx = (float)(a - 1), fy = (float)(b - 1), fz = (float)(c - 1);
    const float dist = sqrtf(fx * fx + fy * fy + fz * fz);
    float emb[4];
    #pragma unroll
    for (int r = 0; r < 4; ++r) {
        const float v = 0.3f * (float)(r + 1);
        const float d = (dist - v) * (1.0f / 0.3f);
        emb[r] = 8.4335731f * sus_f(d + 1.f) * sus_f(1.f - d);
    }
    const float s = (dist > 0.f) ? (1.7320508f / dist) : 0.f;
    const float shv[3] = { fx * s, fy * s, fz * s };
    const float S000 = 0.25f / 27.f;
    const float S1   = 0.25f * 0.57735027f / 27.f;
    const float LNRM = 0.35355339f;

    const int ci = tid >> 3;
    #pragma unroll
    for (int j = 0; j < 8; ++j) {
        const int o = (tid & 7) * 8 + j;
        float val;
        if (ci < 8) {
            const int u = ci;
            if (o < 16) {
                const float* p = w000 + u * 16 + o;
                val = S000 * (emb[0]*p[0] + emb[1]*p[128] + emb[2]*p[256] + emb[3]*p[384]);
                if (t == 13) val += LNRM * w_lin0[u * 16 + o];
            } else {
                const int oo = o - 16, w = oo / 3, m = oo % 3;
                const float* p = w011 + u * 16 + w;
                val = S1 * shv[m] * (emb[0]*p[0] + emb[1]*p[128] + emb[2]*p[256] + emb[3]*p[384]);
            }
        } else {
            const int iu = ci - 8, u = iu / 3, ic = iu % 3;
            if (o < 16) {
                const float* p = w110 + u * 16 + o;
                val = S1 * shv[ic] * (emb[0]*p[0] + emb[1]*p[128] + emb[2]*p[256] + emb[3]*p[384]);
            } else {
                const int oo = o - 16, w = oo / 3, m = oo % 3;
                if (ic == m) {
                    const float* p = w101 + u * 16 + w;
                    val = S1 * (emb[0]*p[0] + emb[1]*p[128] + emb[2]*p[256] + emb[3]*p[384]);
                    if (t == 13) val += LNRM * w_lin1[u * 16 + w];
                } else {
                    val = 0.f;
                }
            }
        }
        const int g = ci >> 3, slot = ci & 7, nt = o >> 4, cc = o & 15;
        const int lane = (g << 4) | cc;
        kw[((size_t)(ta * 4 + nt) * 64 + lane) * 8 + slot] = f2bf(val);
    }
}

// ---------------- main conv kernel ----------------
// LDS tile: [dx=3][y10=10][zp=34][ci=32] bf16 (zp 0/33 are zero pads), 65280 B.
// Within a (dx,y10,zp) row, 16B ci-groups stored at slot ^ ((zp>>1)&3).
template<bool DIRECT>
__global__ __launch_bounds__(256, 2) void conv_mfma(
    const float* __restrict__ x,
    const unsigned short* __restrict__ xb,
    const unsigned short* __restrict__ kw,
    float* __restrict__ out)
{
    __shared__ unsigned short lx[3 * 10 * 34 * 32];   // 65280 B

    const int tid = threadIdx.x;
    const int bid = blockIdx.x;
    // XCD swizzle: bid&7 = XCD; each XCD owns one batch n, X sweeping sequentially.
    const int xcd = bid & 7, idx = bid >> 3;
    const int gid = xcd * 128 + idx;
    const int n = gid >> 7, X = (gid >> 2) & 31, Yg = gid & 3;
    const int Y0 = Yg * 8;
    const int wid = tid >> 6, l = tid & 63, lr = l & 15, lg = l >> 4;

    const bf16x8* kwf = reinterpret_cast<const bf16x8*>(kw);

    // ---- B-frag ring preload (taps 0..2 into slots 0..2); slot ta&3 is
    // consumed at iter ta, slot (ta+3)&3 refilled at iter ta -> never aliases.
    bf16x8 bring[4][4];
    #pragma unroll
    for (int p = 0; p < 3; ++p)
        #pragma unroll
        for (int nt = 0; nt < 4; ++nt)
            bring[p][nt] = kwf[(size_t)(p * 4 + nt) * 64 + l];

    // ---- zero pad slots only (zp=0 and zp=33 of each of the 30 rows) ----
    if (tid < 60) {
        const int row = tid >> 1, zp = (tid & 1) * 33;
        f32x4* dp = reinterpret_cast<f32x4*>(
            reinterpret_cast<char*>(lx) + row * 2176 + zp * 64);
        #pragma unroll
        for (int q = 0; q < 4; ++q) dp[q] = (f32x4)0.f;
    }

    if (DIRECT) {
        // async staging: 30 rows, each = 2048B contiguous in xb and in LDS
        #pragma unroll
        for (int k = 0; k < 8; ++k) {
            const int rr = wid + (k << 2);
            if (rr < 30) {
                const int dx = rr / 10, y6 = rr - dx * 10;
                const int gx = X + dx - 1, gy = Y0 + y6 - 1;
                char* dstrow = reinterpret_cast<char*>(lx) + rr * 2176 + 64;
                if ((unsigned)gx < 32u && (unsigned)gy < 32u) {
                    const char* src = reinterpret_cast<const char*>(xb) +
                        ((size_t)((n * 32 + gx) * 32 + gy) << 11);
                    __builtin_amdgcn_global_load_lds(
                        (const __attribute__((address_space(1))) u32*)(src + l * 16),
                        (__attribute__((address_space(3))) u32*)(dstrow), 16, 0, 0);
                    __builtin_amdgcn_global_load_lds(
                        (const __attribute__((address_space(1))) u32*)(src + 1024 + l * 16),
                        (__attribute__((address_space(3))) u32*)(dstrow + 1024), 16, 0, 0);
                } else {
                    bf16x8 zz = (bf16x8)(short)0;
                    *reinterpret_cast<bf16x8*>(dstrow + l * 16) = zz;
                    *reinterpret_cast<bf16x8*>(dstrow + 1024 + l * 16) = zz;
                }
            }
        }
    } else {
        // fallback: reg-staged f32 -> bf16, same swizzled layout
        for (int it = tid; it < 960; it += 256) {
            const int dx = it / 320, rem = it - dx * 320;
            const int y6 = rem >> 5, z = rem & 31;
            const int gx = X + dx - 1, gy = Y0 + y6 - 1;
            char* row = reinterpret_cast<char*>(lx) + (dx * 10 + y6) * 2176 + (z + 1) * 64;
            if ((unsigned)gx < 32u && (unsigned)gy < 32u) {
                const float4* sp = reinterpret_cast<const float4*>(
                    x + ((size_t)(((n * 32 + gx) * 32 + gy) * 32 + z) << 5));
                const int swz = ((z + 1) >> 1) & 3;
                #pragma unroll
                for (int g = 0; g < 4; ++g) {
                    const float4 lo = sp[2 * g], hi = sp[2 * g + 1];
                    bf16x8 w;
                    w[0] = (short)f2bf(lo.x); w[1] = (short)f2bf(lo.y);
                    w[2] = (short)f2bf(lo.z); w[3] = (short)f2bf(lo.w);
                    w[4] = (short)f2bf(hi.x); w[5] = (short)f2bf(hi.y);
                    w[6] = (short)f2bf(hi.z); w[7] = (short)f2bf(hi.w);
                    *reinterpret_cast<bf16x8*>(row + ((g ^ swz) << 4)) = w;
                }
            } else {
                bf16x8 zz = (bf16x8)(short)0;
                #pragma unroll
                for (int g = 0; g < 4; ++g)
                    *reinterpret_cast<bf16x8*>(row + (g << 4)) = zz;
            }
        }
    }
    __syncthreads();

    // ---- barrier-free tap loop; wave owns y-pair (Y0+2*wid, +1), M=64 ----
    constexpr int TA[19] = {1,3,4,5,7,9,10,11,12,13,14,15,16,17,19,21,22,23,25};
    const char* lxc = reinterpret_cast<const char*>(lx);
    const int yloc = wid * 2;

    f32x4 acc[4][4];
    #pragma unroll
    for (int r = 0; r < 4; ++r)
        #pragma unroll
        for (int nt = 0; nt < 4; ++nt) acc[r][nt] = (f32x4)0.f;

    #pragma unroll
    for (int ta = 0; ta < 19; ++ta) {
        const int t = TA[ta];
        const int a = t / 9, b = (t / 3) % 3, c = t % 3;

        // refill ring slot (ta+3)&3 for tap ta+3 (static index after unroll;
        // distinct from consumed slot ta&3)
        if (ta + 3 < 19) {
            #pragma unroll
            for (int nt = 0; nt < 4; ++nt)
                bring[(ta + 3) & 3][nt] = kwf[(size_t)((ta + 3) * 4 + nt) * 64 + l];
        }

        // batched A-fragment reads (one lgkm group)
        bf16x8 af[4];
        #pragma unroll
        for (int r = 0; r < 4; ++r) {
            const int y10 = yloc + (r >> 1) + b;
            const int zp = 16 * (r & 1) + lr + c;
            const int byte = ((a * 10 + y10) * 34 + zp) * 64 + ((lg ^ ((zp >> 1) & 3)) << 4);
            af[r] = *reinterpret_cast<const bf16x8*>(lxc + byte);
        }

        #pragma unroll
        for (int r = 0; r < 4; ++r)
            #pragma unroll
            for (int nt = 0; nt < 4; ++nt)
                acc[r][nt] = __builtin_amdgcn_mfma_f32_16x16x32_bf16(
                    af[r], bring[ta & 3][nt], acc[r][nt], 0, 0, 0);
    }

    // ---- epilogue: C col = lane&15 (out-ch), row = (lane>>4)*4 + reg (z) ----
    float* ob = out + ((size_t)(((n * 32 + X) * 32 + Y0 + yloc) * 32) << 6);
    #pragma unroll
    for (int r = 0; r < 4; ++r) {
        float* oy = ob + (size_t)(r >> 1) * 2048;
        #pragma unroll
        for (int nt = 0; nt < 4; ++nt)
            #pragma unroll
            for (int reg = 0; reg < 4; ++reg) {
                const int z = 16 * (r & 1) + 4 * lg + reg;
                oy[z * 64 + nt * 16 + lr] = acc[r][nt][reg];
            }
    }
}

extern "C" void kernel_launch(void* const* d_in, const int* in_sizes, int n_in,
                              void* d_out, int out_size, void* d_ws, size_t ws_size,
                              hipStream_t stream) {
    const float* x    = (const float*)d_in[0];
    const float* wl0  = (const float*)d_in[1];
    const float* wl1  = (const float*)d_in[2];
    const float* w000 = (const float*)d_in[3];
    const float* w011 = (const float*)d_in[4];
    const float* w101 = (const float*)d_in[5];
    const float* w110 = (const float*)d_in[6];
    float* out = (float*)d_out;

    unsigned short* kw = (unsigned short*)d_ws;
    const size_t KWB = 77824;               // 19*4*64*8*2
    const size_t XBB = 16777216ull;         // 8*32^3*32*2

    if (ws_size >= KWB + XBB) {
        unsigned short* xb = (unsigned short*)((char*)d_ws + KWB);
        prep_all<<<dim3(4096 + 19), dim3(256), 0, stream>>>(
            x, wl0, wl1, w000, w011, w101, w110, xb, kw, 4096);
        conv_mfma<true><<<dim3(1024), dim3(256), 0, stream>>>(x, xb, kw, out);
    } else {
        prep_all<<<dim3(19), dim3(256), 0, stream>>>(
            x, wl0, wl1, w000, w011, w101, w110, nullptr, kw, 0);
        conv_mfma<false><<<dim3(1024), dim3(256), 0, stream>>>(x, nullptr, kw, out);
    }
}